// Round 19
// baseline (75.605 us; speedup 1.0000x reference)
//
#include <hip/hip_runtime.h>
#include <hip/hip_bf16.h>

// Problem dims (fixed by reference)
#define N_IN   1024     // K
#define N_P    1024     // N (= 32*32 lifted grid)
#define FILT   33
#define PAD    16

typedef __attribute__((ext_vector_type(8))) __bf16 bf16x8;
typedef __attribute__((ext_vector_type(4))) float  f32x4;

#define GLB(p) ((const __attribute__((address_space(1))) unsigned int*)(p))
#define LDSP(p) ((__attribute__((address_space(3))) unsigned int*)(p))

__device__ __forceinline__ unsigned short f2bf(float f) {
    union { __hip_bfloat16 h; unsigned short u; } cv;
    cv.h = __float2bfloat16(f);
    return cv.u;
}

// ---------------------------------------------------------------------------
// Kernel 1: per-row demean + std-normalize, fp32 -> bf16 (r1-proven, ~BW floor)
// ---------------------------------------------------------------------------
__global__ __launch_bounds__(256)
void normalize_kernel(const float* __restrict__ x, __hip_bfloat16* __restrict__ xn)
{
    const int lane = threadIdx.x & 63;
    const int row  = blockIdx.x * 4 + (threadIdx.x >> 6);

    const float4* xr = reinterpret_cast<const float4*>(x + (size_t)row * N_IN);
    float4 v[4];
    float s = 0.f, s2 = 0.f;
#pragma unroll
    for (int i = 0; i < 4; i++) {
        v[i] = xr[i * 64 + lane];
        s  += v[i].x + v[i].y + v[i].z + v[i].w;
        s2 += v[i].x * v[i].x + v[i].y * v[i].y + v[i].z * v[i].z + v[i].w * v[i].w;
    }
#pragma unroll
    for (int off = 32; off > 0; off >>= 1) {
        s  += __shfl_xor(s,  off, 64);
        s2 += __shfl_xor(s2, off, 64);
    }
    const float mu  = s * (1.0f / N_IN);
    const float var = fmaxf(s2 * (1.0f / N_IN) - mu * mu, 0.0f);
    const float inv = 1.0f / (sqrtf(var) + 1e-7f);

    ushort4* outv = reinterpret_cast<ushort4*>(xn + (size_t)row * N_IN);
#pragma unroll
    for (int i = 0; i < 4; i++) {
        ushort4 o;
        o.x = f2bf((v[i].x - mu) * inv);
        o.y = f2bf((v[i].y - mu) * inv);
        o.z = f2bf((v[i].z - mu) * inv);
        o.w = f2bf((v[i].w - mu) * inv);
        outv[i * 64 + lane] = o;
    }
}

// ---------------------------------------------------------------------------
// Kernel 2: Gaussian resolution filter + circular conv along n, fp32 -> bf16
// ---------------------------------------------------------------------------
__global__ __launch_bounds__(256)
void conv_kernel(const float* __restrict__ lm_raw, __hip_bfloat16* __restrict__ lm)
{
    __shared__ float row[N_IN];
    __shared__ float fw[FILT];
    const int tid = threadIdx.x;
    const int p   = blockIdx.x;

    if (tid < FILT) {
        float t = (tid - PAD) * (2.0f / FILT);
        float u = t * 10.0f;            // t / sigma0 (sigma0 = 0.1)
        fw[tid] = expf(-0.5f * u * u);
    }
    reinterpret_cast<float4*>(row)[tid] =
        reinterpret_cast<const float4*>(lm_raw + (size_t)p * N_IN)[tid];
    __syncthreads();

    float fsum = 0.f;
#pragma unroll
    for (int f = 0; f < FILT; f++) fsum += fw[f];
    const float inv = 1.0f / fsum;

    const int n0 = tid * 4;
    float o[4] = {0.f, 0.f, 0.f, 0.f};
#pragma unroll
    for (int f = 0; f < FILT; f++) {
        const float w = fw[f];
#pragma unroll
        for (int j = 0; j < 4; j++)
            o[j] += w * row[(n0 + j + f - PAD) & (N_IN - 1)];
    }
    ushort4 ov;
    ov.x = f2bf(o[0] * inv);
    ov.y = f2bf(o[1] * inv);
    ov.z = f2bf(o[2] * inv);
    ov.w = f2bf(o[3] * inv);
    reinterpret_cast<ushort4*>(lm + (size_t)p * N_IN)[tid] = ov;
}

// ---------------------------------------------------------------------------
// Kernel 3: GEMM  C[M,N] = A[M,K] * B[N,K]^T — wave-async redundant staging.
// 256x256 tile, BK=32, 512 thr (8 waves 2Mx4N), wave 128x64 (acc[8][4]).
// KEY IDEA: barriers never gate data. Each wave stages EXACTLY the bytes it
// reads (A strip: 8 gloads, B strip: 4 gloads) into the SHARED linear LDS
// dests; waves sharing a strip issue byte-identical loads (benign identical-
// value races), so each wave's OWN vmcnt proves readiness (vmcnt is per-wave).
// The per-iter s_barrier is a drain-free skew bound only: no lgkmcnt(0), no
// shared gate. Ring-4 + stage-ahead-2 + skew<1 iter => staging t+2 clobbers
// t-2 only after all waves' reads of <= t-1 completed (proof: MFMA(t-1)
// issued before barrier t implies its ds_reads completed).
// LDS-read, staging-write, MFMA pipes overlap across skewed waves (m114).
// vmcnt accounting: after staging t+2, outstanding = t:12, t+1:12, t+2:12;
// vmcnt(24) drains exactly tile t. Tail: vmcnt(12) at NT-2, vmcnt(0) at NT-1.
// Swizzle key=(row>>1)&3 both sides (0 conflicts, r5-proven); T1 XCD swizzle.
// ---------------------------------------------------------------------------
__global__ __launch_bounds__(512, 2)
void gemm_async(const __hip_bfloat16* __restrict__ A,
                const __hip_bfloat16* __restrict__ B,
                float* __restrict__ C,
                int M, int N, int K)
{
    __shared__ char smem[4][32768];   // ring-4: A[256][64B] @0 | B[256][64B] @16384

    const int tid = threadIdx.x;
    const int l   = tid & 63;
    const int w   = tid >> 6;    // 0..7
    const int wm  = w >> 2;      // 0..1  (M direction, 128 rows)
    const int wn  = w & 3;       // 0..3  (N direction, 64 cols)

    // T1: bijective XCD swizzle (nwg=256 divisible by 8)
    const int o    = blockIdx.x;
    const int lin  = (o & 7) * (gridDim.x >> 3) + (o >> 3);
    const int tn   = lin & 3;          // N/256 = 4
    const int tm   = lin >> 2;         // M/256 = 64
    const size_t bm = (size_t)tm * 256;
    const size_t bn = (size_t)tn * 256;

    // ---- per-wave staging geometry (redundant, shared dests) ----
    // chunk = 16 rows = 64 lanes x 16B; lane: row_in_chunk = l>>2, slot = l&3.
    // swizzle key (row>>1)&3 = (l>>3)&3 (chunk*16, wm*128, wn*64 all 0 mod 8)
    const int sgrp = l >> 2;
    const int scol = 16 * ((l & 3) ^ ((l >> 3) & 3));
    const char* gAw = (const char*)(A + (bm + wm * 128 + sgrp) * (size_t)K) + scol;
    const char* gBw = (const char*)(B + (bn + wn * 64  + sgrp) * (size_t)K) + scol;
    const size_t chunkstep = (size_t)16 * K * 2;    // +16 global rows (bytes)

    // LDS dest for A chunk c: wm*8192 + c*1024 (+ HW lane*16) -> row*64+slot*16
    // LDS dest for B chunk c: 16384 + wn*4096 + c*1024
#define STAGE_W(t, b) do {                                                      \
    const char* a_ = gAw + (size_t)(t) * 64;                                    \
    const char* b_ = gBw + (size_t)(t) * 64;                                    \
    char* L_ = &smem[(b)][0];                                                   \
    _Pragma("unroll")                                                           \
    for (int c_ = 0; c_ < 8; c_++)                                              \
        __builtin_amdgcn_global_load_lds(GLB(a_ + c_ * chunkstep),              \
            LDSP(L_ + wm * 8192 + c_ * 1024), 16, 0, 0);                        \
    _Pragma("unroll")                                                           \
    for (int c_ = 0; c_ < 4; c_++)                                              \
        __builtin_amdgcn_global_load_lds(GLB(b_ + c_ * chunkstep),              \
            LDSP(L_ + 16384 + wn * 4096 + c_ * 1024), 16, 0, 0);                \
} while (0)

    // ---- fragment-read geometry (swizzled ds_read, same involution) ----
    const int lr = l & 15;
    const int kb = l >> 4;                               // 16B k-slot
    const int rslot = 16 * (kb ^ ((lr >> 1) & 3));
    const int abase = (wm * 128 + lr) * 64 + rslot;          // + m*1024
    const int bbase = 16384 + (wn * 64 + lr) * 64 + rslot;   // + n*1024

    f32x4 acc[8][4] = {};
    const int NT = K / 32;                               // 32 K-tiles

    STAGE_W(0, 0);
    STAGE_W(1, 1);

    for (int t = 0; t < NT; ++t) {
        __builtin_amdgcn_s_barrier();        // skew bound ONLY — no drains
        asm volatile("" ::: "memory");       // pin staging below the barrier

        if (t + 2 < NT) {
            STAGE_W(t + 2, (t + 2) & 3);
            asm volatile("s_waitcnt vmcnt(24)" ::: "memory");  // own tile-t copies landed
        } else if (t == NT - 2) {
            asm volatile("s_waitcnt vmcnt(12)" ::: "memory");
        } else {
            asm volatile("s_waitcnt vmcnt(0)" ::: "memory");
        }

        const char* S = &smem[t & 3][0];
        bf16x8 afr[8], bfr[4];
#pragma unroll
        for (int n = 0; n < 4; n++) bfr[n] = *(const bf16x8*)(S + bbase + n * 1024);
#pragma unroll
        for (int m = 0; m < 8; m++) afr[m] = *(const bf16x8*)(S + abase + m * 1024);

        __builtin_amdgcn_s_setprio(1);
#pragma unroll
        for (int m = 0; m < 8; m++)
#pragma unroll
            for (int n = 0; n < 4; n++)
                acc[m][n] = __builtin_amdgcn_mfma_f32_16x16x32_bf16(afr[m], bfr[n], acc[m][n], 0, 0, 0);
        __builtin_amdgcn_s_setprio(0);
    }
#undef STAGE_W

    // epilogue: C/D layout col = lane&15, row = (lane>>4)*4 + reg  [m89/m91]
    const int crow = (l >> 4) * 4;
    const int ccol = l & 15;
#pragma unroll
    for (int m = 0; m < 8; m++)
#pragma unroll
        for (int n = 0; n < 4; n++) {
#pragma unroll
            for (int r = 0; r < 4; r++) {
                const size_t row = bm + wm * 128 + m * 16 + crow + r;
                const size_t col = bn + wn * 64 + n * 16 + ccol;
                C[row * N + col] = acc[m][n][r];
            }
        }
}

// ---------------------------------------------------------------------------
extern "C" void kernel_launch(void* const* d_in, const int* in_sizes, int n_in,
                              void* d_out, int out_size, void* d_ws, size_t ws_size,
                              hipStream_t stream) {
    const float* x      = (const float*)d_in[0];   // [M, 1024] fp32
    const float* lm_raw = (const float*)d_in[1];   // [32, 32, 1024] fp32
    float* out = (float*)d_out;                    // [M, 32, 32] fp32

    const int M = in_sizes[0] / N_IN;              // 16384

    // workspace layout: xn bf16 [M,1024] (32 MiB) | lm bf16 [1024,1024] (2 MiB)
    __hip_bfloat16* xn = (__hip_bfloat16*)d_ws;
    __hip_bfloat16* lm = (__hip_bfloat16*)((char*)d_ws + (size_t)M * N_IN * 2);

    normalize_kernel<<<M / 4, 256, 0, stream>>>(x, xn);
    conv_kernel<<<N_P, 256, 0, stream>>>(lm_raw, lm);

    const int nblk = (M / 256) * (N_P / 256);      // 64 * 4 = 256
    gemm_async<<<nblk, dim3(512), 0, stream>>>(xn, lm, out, M, N_P, N_IN);
}

// Round 20
// 63.621 us; speedup vs baseline: 1.1884x; 1.1884x over previous
//
#include <hip/hip_runtime.h>
#include <hip/hip_bf16.h>

// Problem dims (fixed by reference)
#define N_IN   1024     // K
#define N_P    1024     // N (= 32*32 lifted grid)
#define FILT   33
#define PAD    16

typedef __attribute__((ext_vector_type(8))) __bf16 bf16x8;
typedef __attribute__((ext_vector_type(4))) float  f32x4;

#define GLB(p) ((const __attribute__((address_space(1))) unsigned int*)(p))
#define LDSP(p) ((__attribute__((address_space(3))) unsigned int*)(p))

__device__ __forceinline__ unsigned short f2bf(float f) {
    union { __hip_bfloat16 h; unsigned short u; } cv;
    cv.h = __float2bfloat16(f);
    return cv.u;
}

// ---------------------------------------------------------------------------
// Kernel 1: FUSED prep — normalize (blocks [0, M/4)) + filter-conv (rest).
// Removes one kernel-launch boundary (~1-2 us of the measured ~3.8 us gaps);
// both jobs are BW-bound and share the machine at the HBM floor.
// Branch is block-uniform -> conv-side __syncthreads is legal.
// ---------------------------------------------------------------------------
__global__ __launch_bounds__(256)
void prep_kernel(const float* __restrict__ x, __hip_bfloat16* __restrict__ xn,
                 const float* __restrict__ lm_raw, __hip_bfloat16* __restrict__ lm,
                 int norm_blocks)
{
    __shared__ float rowbuf[N_IN];
    __shared__ float fw[FILT];
    const int tid = threadIdx.x;

    if (blockIdx.x < norm_blocks) {
        // ---- normalize: one wave per row, 4 rows per block (r1-proven) ----
        const int lane = tid & 63;
        const int row  = blockIdx.x * 4 + (tid >> 6);

        const float4* xr = reinterpret_cast<const float4*>(x + (size_t)row * N_IN);
        float4 v[4];
        float s = 0.f, s2 = 0.f;
#pragma unroll
        for (int i = 0; i < 4; i++) {
            v[i] = xr[i * 64 + lane];
            s  += v[i].x + v[i].y + v[i].z + v[i].w;
            s2 += v[i].x * v[i].x + v[i].y * v[i].y + v[i].z * v[i].z + v[i].w * v[i].w;
        }
#pragma unroll
        for (int off = 32; off > 0; off >>= 1) {
            s  += __shfl_xor(s,  off, 64);
            s2 += __shfl_xor(s2, off, 64);
        }
        const float mu  = s * (1.0f / N_IN);
        const float var = fmaxf(s2 * (1.0f / N_IN) - mu * mu, 0.0f);
        const float inv = 1.0f / (sqrtf(var) + 1e-7f);

        ushort4* outv = reinterpret_cast<ushort4*>(xn + (size_t)row * N_IN);
#pragma unroll
        for (int i = 0; i < 4; i++) {
            ushort4 o;
            o.x = f2bf((v[i].x - mu) * inv);
            o.y = f2bf((v[i].y - mu) * inv);
            o.z = f2bf((v[i].z - mu) * inv);
            o.w = f2bf((v[i].w - mu) * inv);
            outv[i * 64 + lane] = o;
        }
    } else {
        // ---- conv: Gaussian resolution filter, circular along n ----
        const int p = blockIdx.x - norm_blocks;

        if (tid < FILT) {
            float t = (tid - PAD) * (2.0f / FILT);
            float u = t * 10.0f;            // t / sigma0 (sigma0 = 0.1)
            fw[tid] = expf(-0.5f * u * u);
        }
        reinterpret_cast<float4*>(rowbuf)[tid] =
            reinterpret_cast<const float4*>(lm_raw + (size_t)p * N_IN)[tid];
        __syncthreads();

        float fsum = 0.f;
#pragma unroll
        for (int f = 0; f < FILT; f++) fsum += fw[f];
        const float inv = 1.0f / fsum;

        const int n0 = tid * 4;
        float o[4] = {0.f, 0.f, 0.f, 0.f};
#pragma unroll
        for (int f = 0; f < FILT; f++) {
            const float w = fw[f];
#pragma unroll
            for (int j = 0; j < 4; j++)
                o[j] += w * rowbuf[(n0 + j + f - PAD) & (N_IN - 1)];
        }
        ushort4 ov;
        ov.x = f2bf(o[0] * inv);
        ov.y = f2bf(o[1] * inv);
        ov.z = f2bf(o[2] * inv);
        ov.w = f2bf(o[3] * inv);
        reinterpret_cast<ushort4*>(lm + (size_t)p * N_IN)[tid] = ov;
    }
}

// ---------------------------------------------------------------------------
// Kernel 2: GEMM  C[M,N] = A[M,K] * B[N,K]^T  — best-known (r11, byte-identical).
// 256x256 tile, BK=32, 512 thr (8 waves 2Mx4N), per-wave 128x64 (acc[8][4]).
// 3-deep LDS ring (3 x 32KB = 96KB), 4 gloads/tile, prefetch distance 2,
// counted s_waitcnt vmcnt(4) (never drains mid-loop; vmcnt(0) last iter).
// Both-sides swizzle involution key=(row>>1)&3 (0 conflicts, r5-proven).
// T1 bijective XCD swizzle (nwg=256); T5 setprio around MFMA clusters.
// Session plateau note: nine schedule variants (r4-r19) land 43-60 us; best
// four 43.3-44.3. Wall = loop (LDS ~13us + MFMA ~13.8us, imperfect overlap
// ~30us) + synchronized 64MB fp32 C-write tail (~10-13us). Not HW roofline
// (MfmaUtil 30%, HBM 26%) but the structure-family plateau at this shape.
// ---------------------------------------------------------------------------
__global__ __launch_bounds__(512, 2)
void gemm_big(const __hip_bfloat16* __restrict__ A,
              const __hip_bfloat16* __restrict__ B,
              float* __restrict__ C,
              int M, int N, int K)
{
    constexpr int BK = 32;                  // K-tile; rows are 64B (4 x 16B slots)
    __shared__ char smem[3][32768];         // ring: A[256][64B] (16K) | B[256][64B] (16K)

    const int tid = threadIdx.x;
    const int l   = tid & 63;
    const int w   = tid >> 6;    // 0..7
    const int wm  = w >> 2;      // 0..1  (M direction, 128 rows each)
    const int wn  = w & 3;       // 0..3  (N direction, 64 cols each)

    // T1: bijective XCD swizzle (nwg=256 divisible by 8)
    const int o    = blockIdx.x;
    const int lin  = (o & 7) * (gridDim.x >> 3) + (o >> 3);
    const int tn   = lin & 3;          // N/256 = 4
    const int tm   = lin >> 2;         // M/256 = 64
    const size_t bm = (size_t)tm * 256;
    const size_t bn = (size_t)tn * 256;

    // ---- staging geometry (per-lane global source, pre-swizzled) ----
    const int srow = w * 16 + (l >> 2);
    const int scol = 16 * ((l & 3) ^ ((l >> 3) & 3));
    const char* gA = (const char*)(A + (bm + srow) * (size_t)K) + scol;
    const char* gB = (const char*)(B + (bn + srow) * (size_t)K) + scol;
    const size_t rowstep = (size_t)128 * K * 2;     // +128 rows (bytes)

#define STAGE(t, b) do {                                                        \
    const char* a0_ = gA + (size_t)(t) * (BK * 2);                              \
    const char* b0_ = gB + (size_t)(t) * (BK * 2);                              \
    char* La_ = &smem[(b)][0]     + w * 1024;                                   \
    char* Lb_ = &smem[(b)][16384] + w * 1024;                                   \
    __builtin_amdgcn_global_load_lds(GLB(a0_),           LDSP(La_),        16, 0, 0); \
    __builtin_amdgcn_global_load_lds(GLB(a0_ + rowstep), LDSP(La_ + 8192), 16, 0, 0); \
    __builtin_amdgcn_global_load_lds(GLB(b0_),           LDSP(Lb_),        16, 0, 0); \
    __builtin_amdgcn_global_load_lds(GLB(b0_ + rowstep), LDSP(Lb_ + 8192), 16, 0, 0); \
} while (0)

    // ---- fragment-read geometry (swizzled ds_read, same involution) ----
    const int lr = l & 15;
    const int kb = l >> 4;                               // k-block of 8 elems
    const int rslot = 16 * (kb ^ ((lr >> 1) & 3));
    const int abase = (wm * 128 + lr) * 64 + rslot;          // + m*1024
    const int bbase = 16384 + (wn * 64 + lr) * 64 + rslot;   // + n*1024

    f32x4 acc[8][4] = {};
    const int NT = K / BK;                               // 32

    STAGE(0, 0);
    STAGE(1, 1);

    int buf = 0;
    for (int t = 0; t < NT; ++t) {
        asm volatile("s_waitcnt lgkmcnt(0)" ::: "memory");  // my prev-iter ds_reads drained
        if (t < NT - 1) asm volatile("s_waitcnt vmcnt(4)" ::: "memory");
        else            asm volatile("s_waitcnt vmcnt(0)" ::: "memory");
        __builtin_amdgcn_s_barrier();
        __builtin_amdgcn_sched_barrier(0);   // nothing crosses the barrier

        {
            const int t2 = t + 2;
            if (t2 < NT) {
                int b2 = buf + 2; if (b2 >= 3) b2 -= 3;
                STAGE(t2, b2);
            }
        }

        const char* Sb = &smem[buf][0];
        bf16x8 bfr[4], afr[4], afr2[4];
#pragma unroll
        for (int n = 0; n < 4; n++) bfr[n]  = *(const bf16x8*)(Sb + bbase + n * 1024);
#pragma unroll
        for (int m = 0; m < 4; m++) afr[m]  = *(const bf16x8*)(Sb + abase + m * 1024);

        __builtin_amdgcn_s_setprio(1);
#pragma unroll
        for (int m = 0; m < 4; m++)
#pragma unroll
            for (int n = 0; n < 4; n++)
                acc[m][n] = __builtin_amdgcn_mfma_f32_16x16x32_bf16(afr[m], bfr[n], acc[m][n], 0, 0, 0);
        __builtin_amdgcn_s_setprio(0);

#pragma unroll
        for (int m = 0; m < 4; m++) afr2[m] = *(const bf16x8*)(Sb + abase + (m + 4) * 1024);

        __builtin_amdgcn_s_setprio(1);
#pragma unroll
        for (int m = 0; m < 4; m++)
#pragma unroll
            for (int n = 0; n < 4; n++)
                acc[m + 4][n] = __builtin_amdgcn_mfma_f32_16x16x32_bf16(afr2[m], bfr[n], acc[m + 4][n], 0, 0, 0);
        __builtin_amdgcn_s_setprio(0);

        if (++buf == 3) buf = 0;
    }
#undef STAGE

    // epilogue: C/D layout col = lane&15, row = (lane>>4)*4 + reg  [m89/m91]
    const int crow = (l >> 4) * 4;
    const int ccol = l & 15;
#pragma unroll
    for (int m = 0; m < 8; m++)
#pragma unroll
        for (int n = 0; n < 4; n++) {
#pragma unroll
            for (int r = 0; r < 4; r++) {
                const size_t row = bm + wm * 128 + m * 16 + crow + r;
                const size_t col = bn + wn * 64 + n * 16 + ccol;
                C[row * N + col] = acc[m][n][r];
            }
        }
}

// ---------------------------------------------------------------------------
extern "C" void kernel_launch(void* const* d_in, const int* in_sizes, int n_in,
                              void* d_out, int out_size, void* d_ws, size_t ws_size,
                              hipStream_t stream) {
    const float* x      = (const float*)d_in[0];   // [M, 1024] fp32
    const float* lm_raw = (const float*)d_in[1];   // [32, 32, 1024] fp32
    float* out = (float*)d_out;                    // [M, 32, 32] fp32

    const int M = in_sizes[0] / N_IN;              // 16384

    // workspace layout: xn bf16 [M,1024] (32 MiB) | lm bf16 [1024,1024] (2 MiB)
    __hip_bfloat16* xn = (__hip_bfloat16*)d_ws;
    __hip_bfloat16* lm = (__hip_bfloat16*)((char*)d_ws + (size_t)M * N_IN * 2);

    const int norm_blocks = M / 4;                 // 4096
    prep_kernel<<<norm_blocks + N_P, 256, 0, stream>>>(x, xn, lm_raw, lm, norm_blocks);

    const int nblk = (M / 256) * (N_P / 256);      // 64 * 4 = 256
    gemm_big<<<nblk, dim3(512), 0, stream>>>(xn, lm, out, M, N_P, N_IN);
}